// Round 2
// baseline (747.882 us; speedup 1.0000x reference)
//
#include <hip/hip_runtime.h>
#include <math.h>

#define T_TOK 8192
#define DM 1024
#define DF 2048
#define NE 16
#define TK 2
#define CAP 1280

typedef __bf16 bf16x8 __attribute__((ext_vector_type(8)));
typedef float f32x4 __attribute__((ext_vector_type(4)));

__device__ __forceinline__ unsigned short f2bf(float f) {
  unsigned int u = __float_as_uint(f);
  unsigned int r = (u + 0x7fffu + ((u >> 16) & 1u)) >> 16;
  return (unsigned short)r;
}

__device__ __forceinline__ void async_copy16(const void* g, void* l) {
  __builtin_amdgcn_global_load_lds(
      (const __attribute__((address_space(1))) void*)g,
      (__attribute__((address_space(3))) void*)l, 16, 0, 0);
}

// ---------------- transpose + fp32->bf16 convert: in (R x Cc) fp32 -> out (Cc x R) bf16
// 64x64 tiles, float4 reads, int4 (8x bf16) writes.
__global__ __launch_bounds__(256) void transpose_conv_kernel(
    const float* __restrict__ in, unsigned short* __restrict__ out, int R, int Cc) {
  __shared__ unsigned short tl[64][72];
  size_t eoff = (size_t)blockIdx.z * R * Cc;
  in += eoff; out += eoff;
  int c0 = blockIdx.x * 64, r0 = blockIdx.y * 64;
  int t = threadIdx.x;
#pragma unroll
  for (int i = 0; i < 4; i++) {
    int r = (t >> 4) + i * 16;
    int c = (t & 15) * 4;
    float4 v = *(const float4*)(in + (size_t)(r0 + r) * Cc + c0 + c);
    tl[c + 0][r] = f2bf(v.x);
    tl[c + 1][r] = f2bf(v.y);
    tl[c + 2][r] = f2bf(v.z);
    tl[c + 3][r] = f2bf(v.w);
  }
  __syncthreads();
#pragma unroll
  for (int i = 0; i < 2; i++) {
    int c = (t >> 3) + i * 32;
    int r = (t & 7) * 8;
    *(int4*)(out + (size_t)(c0 + c) * R + r0 + r) = *(const int4*)&tl[c][r];
  }
}

// ---------------- gating: 4 waves/block, one token per wave; gw staged in LDS
__global__ __launch_bounds__(256) void gate_kernel(
    const float* __restrict__ x, const float* __restrict__ gw,
    int* __restrict__ sel, float* __restrict__ wts) {
  __shared__ float sgw[NE * DM];
  int tid = threadIdx.x, lane = tid & 63, wv = tid >> 6;
  for (int i = tid; i < NE * DM / 4; i += 256)
    ((float4*)sgw)[i] = ((const float4*)gw)[i];
  __syncthreads();
  int t = blockIdx.x * 4 + wv;
  const float4* xr = (const float4*)(x + (size_t)t * DM);
  float4 xv[4];
#pragma unroll
  for (int j = 0; j < 4; j++) xv[j] = xr[j * 64 + lane];
  const float4* g4 = (const float4*)sgw;
  float acc[NE];
#pragma unroll
  for (int e = 0; e < NE; e++) {
    float s = 0.f;
#pragma unroll
    for (int j = 0; j < 4; j++) {
      float4 g = g4[e * 256 + j * 64 + lane];
      s += xv[j].x * g.x + xv[j].y * g.y + xv[j].z * g.z + xv[j].w * g.w;
    }
    acc[e] = s;
  }
#pragma unroll
  for (int e = 0; e < NE; e++) {
    float v = acc[e];
#pragma unroll
    for (int off = 32; off > 0; off >>= 1) v += __shfl_xor(v, off);
    acc[e] = v;
  }
  if (lane == 0) {
    float p[NE];
#pragma unroll
    for (int e = 0; e < NE; e++) p[e] = 1.f / (1.f + expf(-acc[e]));
    int i0 = 0;
#pragma unroll
    for (int e = 1; e < NE; e++) if (p[e] > p[i0]) i0 = e;
    int i1 = (i0 == 0) ? 1 : 0;
#pragma unroll
    for (int e = 0; e < NE; e++) if (e != i0 && p[e] > p[i1]) i1 = e;
    float v0 = p[i0], v1 = p[i1], s = v0 + v1 + 1e-6f;
    sel[2 * t] = i0; sel[2 * t + 1] = i1;
    wts[2 * t] = v0 / s; wts[2 * t + 1] = v1 / s;
  }
}

// ---------------- deterministic rank/capacity scan: one block per expert, token-major order
__global__ __launch_bounds__(256) void scan_kernel(
    const int* __restrict__ sel, int* __restrict__ exp_tok, int* __restrict__ counts) {
  int e = blockIdx.x;
  __shared__ int wsum[4];
  int tid = threadIdx.x, lane = tid & 63, wv = tid >> 6;
  int base = 0;
  for (int p0 = 0; p0 < T_TOK * TK; p0 += 256) {
    int p = p0 + tid;
    int flag = (sel[p] == e) ? 1 : 0;
    unsigned long long b = __ballot(flag);
    int pre = __popcll(b & ((1ull << lane) - 1ull));
    if (lane == 0) wsum[wv] = __popcll(b);
    __syncthreads();
    int wbase = 0;
#pragma unroll
    for (int i = 0; i < 4; i++) if (i < wv) wbase += wsum[i];
    int tot = wsum[0] + wsum[1] + wsum[2] + wsum[3];
    if (flag) {
      int rank = base + wbase + pre;
      if (rank < CAP) exp_tok[e * CAP + rank] = p;
    }
    base += tot;
    __syncthreads();
  }
  if (tid == 0) counts[e] = base < CAP ? base : CAP;
}

// ---------------- gather tokens into padded [E,CAP,DM] bf16 (zero-fill past count)
__global__ __launch_bounds__(128) void gather_kernel(
    const float* __restrict__ x, const int* __restrict__ exp_tok,
    const int* __restrict__ counts, unsigned short* __restrict__ Xp) {
  int i = blockIdx.x, e = blockIdx.y;
  int tid = threadIdx.x;
  unsigned short* dst = Xp + ((size_t)e * CAP + i) * DM;
  int4 pk = make_int4(0, 0, 0, 0);
  if (i < counts[e]) {
    int p = exp_tok[e * CAP + i];
    int t = p >> 1;
    const float4* src = (const float4*)(x + (size_t)t * DM);
    float4 v0 = src[tid * 2];
    float4 v1 = src[tid * 2 + 1];
    union { unsigned short u[8]; int4 v; } q;
    q.u[0] = f2bf(v0.x); q.u[1] = f2bf(v0.y); q.u[2] = f2bf(v0.z); q.u[3] = f2bf(v0.w);
    q.u[4] = f2bf(v1.x); q.u[5] = f2bf(v1.y); q.u[6] = f2bf(v1.z); q.u[7] = f2bf(v1.w);
    pk = q.v;
  }
  ((int4*)dst)[tid] = pk;
}

// ---------------- GEMM1: bf16 MFMA, m97 structure + XOR bank swizzle, GELU, bf16 out
__global__ __launch_bounds__(256) void gemm1_kernel(
    const unsigned short* __restrict__ A, const unsigned short* __restrict__ Bt,
    unsigned short* __restrict__ C, int M, int N, int K,
    size_t sA, size_t sB, size_t sC) {
  __shared__ unsigned short As[128 * 32];
  __shared__ unsigned short Bs[128 * 32];
  A += (size_t)blockIdx.z * sA;
  Bt += (size_t)blockIdx.z * sB;
  C += (size_t)blockIdx.z * sC;
  int m0 = blockIdx.y * 128, n0 = blockIdx.x * 128;
  int tid = threadIdx.x;
  int lane = tid & 63;
  int wv = tid >> 6;
  int wm = (wv >> 1) * 64, wn = (wv & 1) * 64;
  int qd = lane >> 4, lm = lane & 15;
  int sa = (lm >> 1) & 3;  // fragment-read swizzle
  int chunk = (tid & 3) ^ ((tid >> 3) & 3);  // staging-source swizzle

  const unsigned short* a0 = A + (size_t)(m0 + (tid >> 2)) * K + chunk * 8;
  const unsigned short* a1 = a0 + (size_t)64 * K;
  const unsigned short* b0 = Bt + (size_t)(n0 + (tid >> 2)) * K + chunk * 8;
  const unsigned short* b1 = b0 + (size_t)64 * K;
  char* lAs = (char*)As;
  char* lBs = (char*)Bs;

  f32x4 acc[4][4] = {};
  for (int k0 = 0; k0 < K; k0 += 32) {
    __syncthreads();
    async_copy16(a0 + k0, lAs + tid * 16);
    async_copy16(a1 + k0, lAs + (tid + 256) * 16);
    async_copy16(b0 + k0, lBs + tid * 16);
    async_copy16(b1 + k0, lBs + (tid + 256) * 16);
    __syncthreads();
    bf16x8 af[4], bfr[4];
#pragma unroll
    for (int i = 0; i < 4; i++)
      af[i] = *(const bf16x8*)(lAs + (wm + i * 16 + lm) * 64 + (qd ^ sa) * 16);
#pragma unroll
    for (int j = 0; j < 4; j++)
      bfr[j] = *(const bf16x8*)(lBs + (wn + j * 16 + lm) * 64 + (qd ^ sa) * 16);
#pragma unroll
    for (int i = 0; i < 4; i++)
#pragma unroll
      for (int j = 0; j < 4; j++)
        acc[i][j] = __builtin_amdgcn_mfma_f32_16x16x32_bf16(af[i], bfr[j], acc[i][j], 0, 0, 0);
  }
#pragma unroll
  for (int i = 0; i < 4; i++) {
    int row = m0 + wm + i * 16 + qd * 4;
#pragma unroll
    for (int j = 0; j < 4; j++) {
      int col = n0 + wn + j * 16 + lm;
#pragma unroll
      for (int r = 0; r < 4; r++) {
        float v = acc[i][j][r];
        v = 0.5f * v * (1.f + erff(v * 0.70710678118f));
        C[(size_t)(row + r) * N + col] = f2bf(v);
      }
    }
  }
}

// ---------------- GEMM2: same body, epilogue scatters weighted rows to out via atomicAdd
__global__ __launch_bounds__(256) void gemm2_kernel(
    const unsigned short* __restrict__ A, const unsigned short* __restrict__ Bt,
    float* __restrict__ out, const int* __restrict__ exp_tok,
    const int* __restrict__ counts, const float* __restrict__ wts,
    int M, int N, int K, size_t sA, size_t sB) {
  __shared__ unsigned short As[128 * 32];
  __shared__ unsigned short Bs[128 * 32];
  int e = blockIdx.z;
  A += (size_t)e * sA;
  Bt += (size_t)e * sB;
  int m0 = blockIdx.y * 128, n0 = blockIdx.x * 128;
  int tid = threadIdx.x;
  int lane = tid & 63;
  int wv = tid >> 6;
  int wm = (wv >> 1) * 64, wn = (wv & 1) * 64;
  int qd = lane >> 4, lm = lane & 15;
  int sa = (lm >> 1) & 3;
  int chunk = (tid & 3) ^ ((tid >> 3) & 3);

  const unsigned short* a0 = A + (size_t)(m0 + (tid >> 2)) * K + chunk * 8;
  const unsigned short* a1 = a0 + (size_t)64 * K;
  const unsigned short* b0 = Bt + (size_t)(n0 + (tid >> 2)) * K + chunk * 8;
  const unsigned short* b1 = b0 + (size_t)64 * K;
  char* lAs = (char*)As;
  char* lBs = (char*)Bs;

  f32x4 acc[4][4] = {};
  for (int k0 = 0; k0 < K; k0 += 32) {
    __syncthreads();
    async_copy16(a0 + k0, lAs + tid * 16);
    async_copy16(a1 + k0, lAs + (tid + 256) * 16);
    async_copy16(b0 + k0, lBs + tid * 16);
    async_copy16(b1 + k0, lBs + (tid + 256) * 16);
    __syncthreads();
    bf16x8 af[4], bfr[4];
#pragma unroll
    for (int i = 0; i < 4; i++)
      af[i] = *(const bf16x8*)(lAs + (wm + i * 16 + lm) * 64 + (qd ^ sa) * 16);
#pragma unroll
    for (int j = 0; j < 4; j++)
      bfr[j] = *(const bf16x8*)(lBs + (wn + j * 16 + lm) * 64 + (qd ^ sa) * 16);
#pragma unroll
    for (int i = 0; i < 4; i++)
#pragma unroll
      for (int j = 0; j < 4; j++)
        acc[i][j] = __builtin_amdgcn_mfma_f32_16x16x32_bf16(af[i], bfr[j], acc[i][j], 0, 0, 0);
  }
  int cnt = counts[e];
#pragma unroll
  for (int i = 0; i < 4; i++) {
    int base_row = m0 + wm + i * 16 + qd * 4;
#pragma unroll
    for (int r = 0; r < 4; r++) {
      int slot = base_row + r;
      if (slot < cnt) {
        int p = exp_tok[e * CAP + slot];
        float w = wts[p];
        float* orow = out + (size_t)(p >> 1) * DM;
#pragma unroll
        for (int j = 0; j < 4; j++) {
          int col = n0 + wn + j * 16 + lm;
          atomicAdd(orow + col, w * acc[i][j][r]);
        }
      }
    }
  }
}

extern "C" void kernel_launch(void* const* d_in, const int* in_sizes, int n_in,
                              void* d_out, int out_size, void* d_ws, size_t ws_size,
                              hipStream_t stream) {
  (void)in_sizes; (void)n_in; (void)out_size; (void)ws_size;
  const float* x  = (const float*)d_in[0];
  const float* gw = (const float*)d_in[1];
  const float* w1 = (const float*)d_in[2];
  const float* w2 = (const float*)d_in[3];
  float* out = (float*)d_out;

  char* ws = (char*)d_ws;
  unsigned short* w1t = (unsigned short*)ws; ws += (size_t)NE * DM * DF * 2;
  unsigned short* w2t = (unsigned short*)ws; ws += (size_t)NE * DF * DM * 2;
  unsigned short* Xp  = (unsigned short*)ws; ws += (size_t)NE * CAP * DM * 2;
  unsigned short* H   = (unsigned short*)ws; ws += (size_t)NE * CAP * DF * 2;
  int* sel = (int*)ws;       ws += (size_t)T_TOK * TK * 4;
  float* wts = (float*)ws;   ws += (size_t)T_TOK * TK * 4;
  int* exp_tok = (int*)ws;   ws += (size_t)NE * CAP * 4;
  int* counts = (int*)ws;    ws += (size_t)NE * 4;

  hipMemsetAsync(out, 0, (size_t)T_TOK * DM * 4, stream);

  // weights: fp32 -> bf16, transposed to [N,K] per expert
  transpose_conv_kernel<<<dim3(DF / 64, DM / 64, NE), 256, 0, stream>>>(w1, w1t, DM, DF);
  transpose_conv_kernel<<<dim3(DM / 64, DF / 64, NE), 256, 0, stream>>>(w2, w2t, DF, DM);
  // routing
  gate_kernel<<<T_TOK / 4, 256, 0, stream>>>(x, gw, sel, wts);
  scan_kernel<<<NE, 256, 0, stream>>>(sel, exp_tok, counts);
  gather_kernel<<<dim3(CAP, NE), 128, 0, stream>>>(x, exp_tok, counts, Xp);
  // expert FFN
  gemm1_kernel<<<dim3(DF / 128, CAP / 128, NE), 256, 0, stream>>>(
      Xp, w1t, H, CAP, DF, DM, (size_t)CAP * DM, (size_t)DM * DF, (size_t)CAP * DF);
  gemm2_kernel<<<dim3(DM / 128, CAP / 128, NE), 256, 0, stream>>>(
      H, w2t, out, exp_tok, counts, wts, CAP, DM, DF, (size_t)CAP * DF, (size_t)DF * DM);
}